// Round 15
// baseline (135.968 us; speedup 1.0000x reference)
//
#include <hip/hip_runtime.h>
#include <stdint.h>

// TimestepPermutationQuantizer — PASSED r8-r14 with absmax 0.0. The
// arithmetic chain below is BIT-EXACT vs the harness golden — DO NOT CHANGE:
//   scale = fmaxf(mx-mn, 1e-5f) * (1.0f/15.0f)   // XLA const-div rewrite
//   base  = clip(rintf(-mn/scale), 0, 15)        // IEEE f32 div, half-even
//   q     = clip(rintf(v/scale) + base, 0, 15)   // IEEE f32 div
//   out   = (q - base) * scale
// Partition P1: group g members = {gat[g*128+k]}, gat = d_in[1];
// channel c's group = asn[c]>>7, asn = d_in[2].
//
// Perf log: r8 125.5 -> r9 118.7 -> r10 127.7 (shfl sb: DS ops up) ->
// r11 104.7 (subgroup-16 P2, partial barriers) -> r12 209.7 (VGPR spill) ->
// r13 135.0 (scatter quant: DS ops up) -> r14 103.1 (DPP butterfly ~wash;
// stride-3 sb doubled read ops ~wash).
// MODEL UPDATE: DS micro-tuning exhausted; residual gap over the ~58us HBM
// floor is PHASE SERIALIZATION (P2 -> barrier -> P3 within each row + DMA
// vmcnt drain at the bottom barrier).
// r15: software-pipeline across rows, ONE barrier/row:
//   iter k: prefetch row k+1 -> REGS  ||  P2(row k) -> sb[cur]
//           ||  P3(row k-1) from rowbuf[cur^1]+sb[cur^1]  -> out
//           then stage regs -> rowbuf[cur^1] (wave-local slice: P3 reads and
//           staging writes are both tid-partitioned -> no cross-wave hazard)
//           __syncthreads()
// Reg staging (not global_load_lds) -> no barrier-wide vmcnt drains at all.
// sb back to float2 (one b64 per lookup; r14's stride-3 split it into 2 ops).
// LDS 33KB -> 4 blocks/CU x 8 waves = 32 waves/CU.

constexpr int C     = 4096;
constexpr int GS    = 128;
constexpr int NG    = C / GS;          // 32 groups
constexpr int BLOCK = 512;             // 8 waves
constexpr int GPW   = 4;               // groups per wave (16-lane subgroups)
constexpr int VECS  = C / 4 / BLOCK;   // 2 float4 per thread

template<int CTRL>
__device__ __forceinline__ float dpp_mov(float x) {
    // VALU-pipe cross-lane move (DPP), no DS usage.
    return __int_as_float(__builtin_amdgcn_update_dpp(
        0, __float_as_int(x), CTRL, 0xF, 0xF, true));
}

__device__ __forceinline__ void quant_row(
    const float* rcbase, const float2* sbc, float* outrow,
    int tid, const uint32_t* gpack)
{
    const float4* rc4 = reinterpret_cast<const float4*>(rcbase);
    float4*       or4 = reinterpret_cast<float4*>(outrow);
    #pragma unroll
    for (int i = 0; i < VECS; ++i) {
        const float4   v  = rc4[tid + i * BLOCK];   // conflict-free b128
        const uint32_t gp = gpack[i];
        float4 o;
        { const float2 p = sbc[gp & 31u];
          o.x = (fminf(fmaxf(rintf(v.x / p.x) + p.y, 0.0f), 15.0f) - p.y) * p.x; }
        { const float2 p = sbc[(gp >> 8) & 31u];
          o.y = (fminf(fmaxf(rintf(v.y / p.x) + p.y, 0.0f), 15.0f) - p.y) * p.x; }
        { const float2 p = sbc[(gp >> 16) & 31u];
          o.z = (fminf(fmaxf(rintf(v.z / p.x) + p.y, 0.0f), 15.0f) - p.y) * p.x; }
        { const float2 p = sbc[(gp >> 24) & 31u];
          o.w = (fminf(fmaxf(rintf(v.w / p.x) + p.y, 0.0f), 15.0f) - p.y) * p.x; }
        or4[tid + i * BLOCK] = o;
    }
}

__global__ __launch_bounds__(BLOCK, 8) void tpq_kernel(
    const float* __restrict__ x,
    const int*   __restrict__ gat,   // d_in[1]: group g = {gat[g*128+k]}
    const int*   __restrict__ asn,   // d_in[2]: channel c -> pos asn[c]
    float*       __restrict__ out,
    int rows)
{
    __shared__ float  rowbuf[2][C];
    __shared__ float2 sb[2][NG];

    const int tid  = threadIdx.x;
    const int wave = tid >> 6;
    const int lane = tid & 63;
    const int sub  = lane >> 4;        // subgroup within wave
    const int sl   = lane & 15;        // lane within subgroup
    const int g    = wave * GPW + sub; // this lane's P2 group

    // ---- row-invariant preloads ----
    int pidx[8];
    {
        const int4* g4 = reinterpret_cast<const int4*>(gat + g * GS + sl * 8);
        const int4 a = g4[0], b = g4[1];
        pidx[0] = a.x; pidx[1] = a.y; pidx[2] = a.z; pidx[3] = a.w;
        pidx[4] = b.x; pidx[5] = b.y; pidx[6] = b.z; pidx[7] = b.w;
    }
    uint32_t gpack[VECS];              // 4x 5-bit group ids per u32
    #pragma unroll
    for (int i = 0; i < VECS; ++i) {
        const int4 a = reinterpret_cast<const int4*>(asn)[tid + i * BLOCK];
        gpack[i] = (uint32_t)(a.x >> 7)        | ((uint32_t)(a.y >> 7) << 8)
                 | ((uint32_t)(a.z >> 7) << 16) | ((uint32_t)(a.w >> 7) << 24);
    }

    int r = blockIdx.x;
    const int stride = gridDim.x;

    // ---- prologue: stage row r into rowbuf[0] via regs ----
    {
        const float4* x4  = reinterpret_cast<const float4*>(x + (size_t)r * C);
        float4*       rw4 = reinterpret_cast<float4*>(rowbuf[0]);
        #pragma unroll
        for (int i = 0; i < VECS; ++i) rw4[tid + i * BLOCK] = x4[tid + i * BLOCK];
        __syncthreads();
    }

    int cur = 0, rp = -1;
    while (true) {
        const int  rn = r + stride;
        const bool hn = rn < rows;

        // ---- prefetch row rn into registers (lands during P2+P3) ----
        float4 vn[VECS];
        if (hn) {
            const float4* nx4 = reinterpret_cast<const float4*>(x + (size_t)rn * C);
            #pragma unroll
            for (int i = 0; i < VECS; ++i) vn[i] = nx4[tid + i * BLOCK];
        }

        // ---- P2(r): gather + in-lane tree + 16-lane DPP butterfly ----
        {
            const float* rc = rowbuf[cur];
            const float a0 = rc[pidx[0]], a1 = rc[pidx[1]];
            const float a2 = rc[pidx[2]], a3 = rc[pidx[3]];
            const float a4 = rc[pidx[4]], a5 = rc[pidx[5]];
            const float a6 = rc[pidx[6]], a7 = rc[pidx[7]];
            float mx = fmaxf(fmaxf(fmaxf(a0, a1), fmaxf(a2, a3)),
                             fmaxf(fmaxf(a4, a5), fmaxf(a6, a7)));
            float mn = fminf(fminf(fminf(a0, a1), fminf(a2, a3)),
                             fminf(fminf(a4, a5), fminf(a6, a7)));
            mx = fmaxf(mx, dpp_mov<0xB1>(mx));   // quad_perm xor1
            mn = fminf(mn, dpp_mov<0xB1>(mn));
            mx = fmaxf(mx, dpp_mov<0x4E>(mx));   // quad_perm xor2
            mn = fminf(mn, dpp_mov<0x4E>(mn));
            mx = fmaxf(mx, dpp_mov<0x141>(mx));  // row_half_mirror xor4
            mn = fminf(mn, dpp_mov<0x141>(mn));
            mx = fmaxf(mx, dpp_mov<0x140>(mx));  // row_mirror xor8
            mn = fminf(mn, dpp_mov<0x140>(mn));
            if (sl == 0) {
                const float s = fmaxf(mx - mn, 1e-5f) * (1.0f / 15.0f);
                const float b = fminf(fmaxf(rintf(-mn / s), 0.0f), 15.0f);
                sb[cur][g] = make_float2(s, b);
            }
        }

        // ---- P3(rp): quant previous row (independent of P2, no barrier) ---
        if (rp >= 0)
            quant_row(rowbuf[cur ^ 1], sb[cur ^ 1], out + (size_t)rp * C,
                      tid, gpack);

        if (!hn) break;

        // ---- stage rn over the just-consumed wave-local slice ----
        {
            float4* rw4 = reinterpret_cast<float4*>(rowbuf[cur ^ 1]);
            #pragma unroll
            for (int i = 0; i < VECS; ++i) rw4[tid + i * BLOCK] = vn[i];
        }
        __syncthreads();   // ONE barrier/row: sb[cur] + staged rowbuf visible
        rp = r; r = rn; cur ^= 1;
    }

    // ---- epilogue: quant the final row (sb[cur] from last P2) ----
    __syncthreads();
    quant_row(rowbuf[cur], sb[cur], out + (size_t)r * C, tid, gpack);
}

extern "C" void kernel_launch(void* const* d_in, const int* in_sizes, int n_in,
                              void* d_out, int out_size, void* d_ws, size_t ws_size,
                              hipStream_t stream) {
    const float* x   = (const float*)d_in[0];
    const int*   gat = (const int*)d_in[1];   // perm (gather) — P1 partition
    const int*   asn = (const int*)d_in[2];   // inverse perm (assignment)
    float* out = (float*)d_out;

    const int rows = in_sizes[0] / C;            // 16384
    const int nblk = rows < 2048 ? rows : 2048;  // 8 rows/block grid-stride

    tpq_kernel<<<nblk, BLOCK, 0, stream>>>(x, gat, asn, out, rows);
}

// Round 16
// 106.462 us; speedup vs baseline: 1.2772x; 1.2772x over previous
//
#include <hip/hip_runtime.h>
#include <stdint.h>

// TimestepPermutationQuantizer — PASSED r8-r15 with absmax 0.0. The
// arithmetic chain below is BIT-EXACT vs the harness golden — DO NOT CHANGE:
//   scale = fmaxf(mx-mn, 1e-5f) * (1.0f/15.0f)   // XLA const-div rewrite
//   base  = clip(rintf(-mn/scale), 0, 15)        // IEEE f32 div, half-even
//   q     = clip(rintf(v/scale) + base, 0, 15)   // IEEE f32 div
//   out   = (q - base) * scale
// Partition P1: group g members = {gat[g*128+k]}, gat = d_in[1];
// channel c's group = asn[c]>>7, asn = d_in[2].
//
// Perf log: r8 125.5 -> r9 118.7 -> r10 127.7 (+DS ops) -> r11 104.7 ->
// r12 209.7 (VGPR spill) -> r13 135.0 (+DS ops) -> r14 103.1 (DPP ~wash) ->
// r15 136.0 (reg-staged 1-barrier pipeline: +DS writes/pressure, regressed).
// PATTERN: intra-block pipelining keeps losing; work-removal plateaus at
// ~103 vs ~62-64us HBM floor. Constant factor: 4 barrier-coupled blocks/CU
// can't hide the per-row load->stats->quant latency chain (r8 occupancy 42%).
// r16: INTER-BLOCK TLP instead. One row per block, BLOCK=256, grid=16384,
// LDS 16.6KB -> 8 blocks/CU, all state transient (no spill surface):
//   DMA row (global_load_lds x4/wave) -> barrier ->
//   P2: 16 subgroups x 2 groups (in-lane tree + 4-level DPP butterfly,
//       indices loaded fresh from L2-hot gat) -> barrier ->
//   P3: 4x {b128 row read, int4 asn read, 4x sb b64, quant, 16B store}.
// While one block sits at a barrier/DMA-drain, 7 others compute.

constexpr int C     = 4096;
constexpr int GS    = 128;
constexpr int NG    = C / GS;          // 32 groups
constexpr int BLOCK = 256;             // 4 waves; 16 subgroups of 16 lanes
constexpr int VECS  = C / 4 / BLOCK;   // 4 float4 per thread in P3

typedef const __attribute__((address_space(1))) uint32_t glb_u32;
typedef __attribute__((address_space(3))) uint32_t lds_u32;

template<int CTRL>
__device__ __forceinline__ float dpp_mov(float x) {
    // VALU-pipe cross-lane move (DPP), no DS usage.
    return __int_as_float(__builtin_amdgcn_update_dpp(
        0, __float_as_int(x), CTRL, 0xF, 0xF, true));
}

__global__ __launch_bounds__(BLOCK, 8) void tpq_kernel(
    const float* __restrict__ x,
    const int*   __restrict__ gat,   // d_in[1]: group g = {gat[g*128+k]}
    const int*   __restrict__ asn,   // d_in[2]: channel c -> pos asn[c]
    float*       __restrict__ out)
{
    __shared__ float  rowbuf[C];
    __shared__ float2 sb[NG];

    const int tid  = threadIdx.x;
    const int wave = tid >> 6;
    const int lane = tid & 63;
    const int sg   = tid >> 4;         // subgroup 0..15
    const int sl   = tid & 15;         // lane within subgroup

    const size_t r = blockIdx.x;       // one row per block

    // ---- stage row r into LDS via DMA (4 chunks per wave) ----
    #pragma unroll
    for (int i = 0; i < 4; ++i) {
        const float* g = x + r * C + i * 1024 + wave * 256 + lane * 4;
        float*       l = rowbuf + i * 1024 + wave * 256;
        __builtin_amdgcn_global_load_lds((glb_u32*)(uintptr_t)g,
                                         (lds_u32*)(uintptr_t)l, 16, 0, 0);
    }
    __syncthreads();   // DMA drained (vmcnt) + all waves see rowbuf

    // ---- P2: each 16-lane subgroup computes 2 groups ----
    #pragma unroll
    for (int gi = 0; gi < 2; ++gi) {
        const int g = sg * 2 + gi;
        // indices loaded fresh (gat is 16KB, L2-hot chip-wide; one-shot use)
        const int4* g4 = reinterpret_cast<const int4*>(gat + g * GS + sl * 8);
        const int4 ia = g4[0], ib = g4[1];
        const float a0 = rowbuf[ia.x], a1 = rowbuf[ia.y];
        const float a2 = rowbuf[ia.z], a3 = rowbuf[ia.w];
        const float a4 = rowbuf[ib.x], a5 = rowbuf[ib.y];
        const float a6 = rowbuf[ib.z], a7 = rowbuf[ib.w];
        float mx = fmaxf(fmaxf(fmaxf(a0, a1), fmaxf(a2, a3)),
                         fmaxf(fmaxf(a4, a5), fmaxf(a6, a7)));
        float mn = fminf(fminf(fminf(a0, a1), fminf(a2, a3)),
                         fminf(fminf(a4, a5), fminf(a6, a7)));
        mx = fmaxf(mx, dpp_mov<0xB1>(mx));   // quad_perm xor1
        mn = fminf(mn, dpp_mov<0xB1>(mn));
        mx = fmaxf(mx, dpp_mov<0x4E>(mx));   // quad_perm xor2
        mn = fminf(mn, dpp_mov<0x4E>(mn));
        mx = fmaxf(mx, dpp_mov<0x141>(mx));  // row_half_mirror xor4
        mn = fminf(mn, dpp_mov<0x141>(mn));
        mx = fmaxf(mx, dpp_mov<0x140>(mx));  // row_mirror xor8
        mn = fminf(mn, dpp_mov<0x140>(mn));
        if (sl == 0) {
            const float s = fmaxf(mx - mn, 1e-5f) * (1.0f / 15.0f);
            const float b = fminf(fmaxf(rintf(-mn / s), 0.0f), 15.0f);
            sb[g] = make_float2(s, b);
        }
    }
    __syncthreads();   // sb visible

    // ---- P3: linear elementwise quant/dequant, fully coalesced ----
    const float4* rc4 = reinterpret_cast<const float4*>(rowbuf);
    const int4*   as4 = reinterpret_cast<const int4*>(asn);
    float4*       or4 = reinterpret_cast<float4*>(out + r * C);
    #pragma unroll
    for (int i = 0; i < VECS; ++i) {
        const int    idx = tid + i * BLOCK;
        const int4   a   = as4[idx];           // L2-hot, one-shot
        const float4 v   = rc4[idx];           // conflict-free b128
        float4 o;
        { const float2 p = sb[a.x >> 7];
          o.x = (fminf(fmaxf(rintf(v.x / p.x) + p.y, 0.0f), 15.0f) - p.y) * p.x; }
        { const float2 p = sb[a.y >> 7];
          o.y = (fminf(fmaxf(rintf(v.y / p.x) + p.y, 0.0f), 15.0f) - p.y) * p.x; }
        { const float2 p = sb[a.z >> 7];
          o.z = (fminf(fmaxf(rintf(v.z / p.x) + p.y, 0.0f), 15.0f) - p.y) * p.x; }
        { const float2 p = sb[a.w >> 7];
          o.w = (fminf(fmaxf(rintf(v.w / p.x) + p.y, 0.0f), 15.0f) - p.y) * p.x; }
        or4[idx] = o;
    }
}

extern "C" void kernel_launch(void* const* d_in, const int* in_sizes, int n_in,
                              void* d_out, int out_size, void* d_ws, size_t ws_size,
                              hipStream_t stream) {
    const float* x   = (const float*)d_in[0];
    const int*   gat = (const int*)d_in[1];   // perm (gather) — P1 partition
    const int*   asn = (const int*)d_in[2];   // inverse perm (assignment)
    float* out = (float*)d_out;

    const int rows = in_sizes[0] / C;         // 16384 — one block per row

    tpq_kernel<<<rows, BLOCK, 0, stream>>>(x, gat, asn, out);
}